// Round 1
// 80.115 us; speedup vs baseline: 1.1008x; 1.1008x over previous
//
#include <hip/hip_runtime.h>

#define NUM_PTS 1024
#define NBATCH 128
#define BT 512                        // 8 waves per block
#define NW 8                          // waves per block
#define QW 128                        // q points per wave (8 x 128 = all 1024 q in-block)
#define R 8                           // rows per lane (64 lanes x 8 = 512 rows per block)
#define CHAMF_SCALE (1.0f / 1024.0f)
#define KLD_SCALE   (-0.5f * 0.1f / 32.0f)

// Session note (R16): measured 88.2us decomposes as 40.3us harness ws-poison
// fill (256MiB, inside the timed graph, untouchable) + ~39.5 chamfer + ~5
// reduce + ~3 gaps. This round: fuse the 8 q-chunks into one 8-wave block so
// the cross-chunk row-min completes in LDS -> kills the 8.4MB ws round-trip
// and shrinks reduce to a 1-block kernel. Main loop is byte-identical to the
// verified 3.5-inst/eval floor (pk_fp32 rate-neutral R4, dot2 regressed R15,
// MFMA epilogue loses). Predicted ~82us.
__global__ __launch_bounds__(BT, 4) void chamfer_fused(
    const float* __restrict__ recon_x,
    const float* __restrict__ x,
    float* __restrict__ ws)
{
    // 512 blocks: dir (2) x batch (128) x row-half (2)
    const int bid = blockIdx.x;
    const int dir = bid & 1;
    const int b   = (bid >> 1) & 127;
    const int rh  = bid >> 8;                 // 0/1: rows [0,512) / [512,1024)
    const int w   = threadIdx.x >> 6;         // wave 0..7 -> q window w*128
    const int lt  = threadIdx.x & 63;

    __shared__ float sq[NW][4][QW];           // 16 KB: per-wave q planes
    __shared__ float comb[NW][BT];            // 16 KB: per-wave row-min partials
    __shared__ float red[NW];

    // --- stage this wave's 128-pt q window (wave-private: no barrier needed)
    {
        const float* qsrc = (dir == 0 ? recon_x : x)
            + (size_t)b * NUM_PTS * 3 + (size_t)(w * QW) * 3;
#pragma unroll
        for (int i = 0; i < 2; ++i) {
            const int p = i * 64 + lt;
            const float qx = qsrc[3 * p + 0];
            const float qy = qsrc[3 * p + 1];
            const float qz = qsrc[3 * p + 2];
            sq[w][0][p] = qx;
            sq[w][1][p] = qy;
            sq[w][2][p] = qz;
            sq[w][3][p] = fmaf(qx, qx, fmaf(qy, qy, qz * qz));
        }
    }

    // --- own 8 contiguous rows: 6 coalesced float4 loads, keep -2*coord
    const float* rp = (dir == 0 ? x : recon_x)
        + (size_t)b * NUM_PTS * 3 + (size_t)rh * 512 * 3;
    float vx[R], vy[R], vz[R], m[R];
    {
        float buf[24];
        const float4* __restrict__ s4 = (const float4*)(rp + 24 * lt);
        float4* bp = (float4*)buf;
#pragma unroll
        for (int i = 0; i < 6; ++i) bp[i] = s4[i];
#pragma unroll
        for (int k = 0; k < R; ++k) {
            vx[k] = -2.0f * buf[3 * k + 0];
            vy[k] = -2.0f * buf[3 * k + 1];
            vz[k] = -2.0f * buf[3 * k + 2];
            m[k]  = 1e30f;
        }
    }

    // --- 32 groups x 4 qpts over this wave's q window (verified inner loop)
    const float4* __restrict__ qxp = (const float4*)sq[w][0];
    const float4* __restrict__ qyp = (const float4*)sq[w][1];
    const float4* __restrict__ qzp = (const float4*)sq[w][2];
    const float4* __restrict__ q2p = (const float4*)sq[w][3];
#pragma unroll 2
    for (int g = 0; g < QW / 4; ++g) {
        const float4 qx = qxp[g];
        const float4 qy = qyp[g];
        const float4 qz = qzp[g];
        const float4 q2 = q2p[g];
#pragma unroll
        for (int r = 0; r < R; ++r) {
            const float d0 = fmaf(vx[r], qx.x, fmaf(vy[r], qy.x, fmaf(vz[r], qz.x, q2.x)));
            const float d1 = fmaf(vx[r], qx.y, fmaf(vy[r], qy.y, fmaf(vz[r], qz.y, q2.y)));
            m[r] = fminf(fminf(m[r], d0), d1);            // v_min3_f32
        }
#pragma unroll
        for (int r = 0; r < R; ++r) {
            const float d2 = fmaf(vx[r], qx.z, fmaf(vy[r], qy.z, fmaf(vz[r], qz.z, q2.z)));
            const float d3 = fmaf(vx[r], qx.w, fmaf(vy[r], qy.w, fmaf(vz[r], qz.w, q2.w)));
            m[r] = fminf(fminf(m[r], d2), d3);
        }
    }

    // --- epilogue: publish per-wave row-min partials (+r2), fold 8 waves,
    //     block-sum, one float per block. Write pattern is 16-way banked but
    //     epilogue-only (runs once): negligible vs the 3.7k-inst main loop.
#pragma unroll
    for (int k = 0; k < R; ++k) {
        const float r2 = 0.25f * fmaf(vx[k], vx[k], fmaf(vy[k], vy[k], vz[k] * vz[k]));
        comb[w][8 * lt + k] = m[k] + r2;
    }
    __syncthreads();

    const int t = threadIdx.x;                // local row index 0..511
    float v = comb[0][t];                     // lanes read consecutive addrs: conflict-free
#pragma unroll
    for (int ww = 1; ww < NW; ++ww) v = fminf(v, comb[ww][t]);

    for (int off = 32; off > 0; off >>= 1)
        v += __shfl_down(v, off, 64);
    if (lt == 0) red[w] = v;
    __syncthreads();
    if (t == 0) {
        float s = 0.0f;
#pragma unroll
        for (int ww = 0; ww < NW; ++ww) s += red[ww];
        ws[bid] = s;                          // 512 floats total (ws fully overwritten)
    }
}

// 1 block: sum 512 chamfer block-partials + KLD over 4096 latents.
// Plain (non-atomic) out[0] store: no init dispatch, no race.
__global__ __launch_bounds__(BT) void final_reduce(
    const float* __restrict__ ws,
    const float* __restrict__ mu,
    const float* __restrict__ logvar,
    float* __restrict__ out)
{
    const int t = threadIdx.x;
    float v = ws[t] * CHAMF_SCALE;

    // 4096 latents, 8 per thread, float4 x2 loads
    const float4* mp = (const float4*)mu + 2 * t;
    const float4* lp = (const float4*)logvar + 2 * t;
    float kv = 0.0f;
#pragma unroll
    for (int i = 0; i < 2; ++i) {
        const float4 mm = mp[i];
        const float4 lv = lp[i];
        kv += (1.0f + lv.x - mm.x * mm.x - expf(lv.x));
        kv += (1.0f + lv.y - mm.y * mm.y - expf(lv.y));
        kv += (1.0f + lv.z - mm.z * mm.z - expf(lv.z));
        kv += (1.0f + lv.w - mm.w * mm.w - expf(lv.w));
    }
    v += kv * KLD_SCALE;

    for (int off = 32; off > 0; off >>= 1)
        v += __shfl_down(v, off, 64);

    __shared__ float red[BT / 64];
    if ((t & 63) == 0) red[t >> 6] = v;
    __syncthreads();
    if (t == 0) {
        float s = 0.0f;
#pragma unroll
        for (int ww = 0; ww < BT / 64; ++ww) s += red[ww];
        out[0] = s;
    }
}

extern "C" void kernel_launch(void* const* d_in, const int* in_sizes, int n_in,
                              void* d_out, int out_size, void* d_ws, size_t ws_size,
                              hipStream_t stream) {
    const float* recon_x = (const float*)d_in[0];
    const float* x       = (const float*)d_in[1];
    const float* mu      = (const float*)d_in[2];
    const float* logvar  = (const float*)d_in[3];
    float* out = (float*)d_out;
    float* ws  = (float*)d_ws;               // uses 2 KB (512 block partials)

    chamfer_fused<<<512, BT, 0, stream>>>(recon_x, x, ws);
    final_reduce<<<1, BT, 0, stream>>>(ws, mu, logvar, out);
}

// Round 2
// 78.727 us; speedup vs baseline: 1.1202x; 1.0176x over previous
//
#include <hip/hip_runtime.h>

#define NUM_PTS 1024
#define NBATCH 128
#define BT 512                        // 8 waves per block
#define NW 8
#define QW 128                        // q columns per wave window
#define R 8                           // rows per lane (64*8 = 512 rows/block)
#define NSTEP 64
#define CHAMF_SCALE (1.0f / 1024.0f)
#define KLD_SCALE   (-0.5f * 0.1f / 32.0f)

// ws layout (floats): [256 blocks][1024] col partials | [256] row sums | [128] batch totals
#define COL_OFF 0
#define RS_OFF  (256 * 1024)
#define WS2_OFF (RS_OFF + 256)

// R18: shared-P rotation scheme. P[i][j] computed ONCE (was 2x for the two
// chamfer directions): each eval folds into row-min m[r] AND a per-column
// accumulator that rotates across lanes (lane l at step s owns col (l+s)&63,
// reads q from a DOUBLED ring so offsets are ds_read immediates, rotates via
// ds_bpermute). 5.125 VALU/unique-eval vs 7.0 before -> predict chamfer
// 36 -> ~26us. |x|^2 moves INSIDE the fma chain (col-min needs it per-row).
__global__ __launch_bounds__(BT, 4) void chamfer_shared(
    const float* __restrict__ recon_x,
    const float* __restrict__ x,
    float* __restrict__ ws)
{
    const int bid = blockIdx.x;          // b*2 + rh
    const int b   = bid >> 1;
    const int rh  = bid & 1;
    const int w   = threadIdx.x >> 6;
    const int lt  = threadIdx.x & 63;
    const int t   = threadIdx.x;

    __shared__ float4 ring[NW][2][2 * NSTEP];   // doubled q rings, 32 KB
    __shared__ float  comb[NW][BT];             // row-min combine, 16 KB
    __shared__ float  red[NW];

    // --- stage this wave's 128 q columns (recon pts), duplicated for wrap-free ring
    {
        const float* qsrc = recon_x + (size_t)b * NUM_PTS * 3 + (size_t)(w * QW) * 3;
#pragma unroll
        for (int i = 0; i < 2; ++i) {
            const int c = i * 64 + lt;
            const float qx = qsrc[3 * c + 0];
            const float qy = qsrc[3 * c + 1];
            const float qz = qsrc[3 * c + 2];
            const float4 q4 = make_float4(qx, qy, qz,
                                          fmaf(qx, qx, fmaf(qy, qy, qz * qz)));
            ring[w][i][lt]      = q4;
            ring[w][i][lt + 64] = q4;            // duplicate: entry e=l+s needs e<128
        }
    }

    // --- own 8 contiguous rows (x pts): 6 coalesced float4 loads, keep -2*coord
    const float* rp = x + (size_t)b * NUM_PTS * 3 + (size_t)rh * 512 * 3;
    float vx[R], vy[R], vz[R], r2[R], m[R];
    {
        float buf[24];
        const float4* __restrict__ s4 = (const float4*)(rp + 24 * lt);
        float4* bp = (float4*)buf;
#pragma unroll
        for (int i = 0; i < 6; ++i) bp[i] = s4[i];
#pragma unroll
        for (int k = 0; k < R; ++k) {
            vx[k] = -2.0f * buf[3 * k + 0];
            vy[k] = -2.0f * buf[3 * k + 1];
            vz[k] = -2.0f * buf[3 * k + 2];
            r2[k] = 0.25f * fmaf(vx[k], vx[k], fmaf(vy[k], vy[k], vz[k] * vz[k]));
            m[k]  = 1e30f;
        }
    }

    // --- 64 rotation steps: 2 cols/lane/step (one per ring), full distance in chain
    const float4* __restrict__ r0 = &ring[w][0][lt];
    const float4* __restrict__ r1 = &ring[w][1][lt];
    float ca = 1e30f, cb = 1e30f;
    const int rotaddr = ((lt + 1) & 63) << 2;    // new[l] = old[(l+1)&63]

#pragma unroll 16
    for (int s = 0; s < NSTEP; ++s) {
        const float4 qa = r0[s];                 // ds_read_b128, offset immediate
        const float4 qb = r1[s];
        float da[R], db[R];
#pragma unroll
        for (int r = 0; r < R; ++r) {
            da[r] = fmaf(vx[r], qa.x, fmaf(vy[r], qa.y, fmaf(vz[r], qa.z, r2[r] + qa.w)));
            db[r] = fmaf(vx[r], qb.x, fmaf(vy[r], qb.y, fmaf(vz[r], qb.z, r2[r] + qb.w)));
        }
#pragma unroll
        for (int r = 0; r < R; ++r)
            m[r] = fminf(fminf(m[r], da[r]), db[r]);       // v_min3_f32
        {
            const float t0 = fminf(fminf(da[0], da[1]), da[2]);
            const float t1 = fminf(fminf(da[3], da[4]), da[5]);
            const float t2 = fminf(fminf(da[6], da[7]), ca);
            ca = fminf(fminf(t0, t1), t2);
        }
        {
            const float u0 = fminf(fminf(db[0], db[1]), db[2]);
            const float u1 = fminf(fminf(db[3], db[4]), db[5]);
            const float u2 = fminf(fminf(db[6], db[7]), cb);
            cb = fminf(fminf(u0, u1), u2);
        }
        ca = __int_as_float(__builtin_amdgcn_ds_bpermute(rotaddr, __float_as_int(ca)));
        cb = __int_as_float(__builtin_amdgcn_ds_bpermute(rotaddr, __float_as_int(cb)));
    }

    // --- col partials: after 64 rotates lane l holds its own col l (+64)
    {
        float* cp = ws + COL_OFF + (size_t)bid * 1024 + w * QW;
        cp[lt]      = ca;
        cp[64 + lt] = cb;
    }

    // --- row-min fold across waves (m already includes r2), block sum
#pragma unroll
    for (int k = 0; k < R; ++k)
        comb[w][R * lt + k] = m[k];
    __syncthreads();

    float v = comb[0][t];
#pragma unroll
    for (int ww = 1; ww < NW; ++ww) v = fminf(v, comb[ww][t]);
    for (int off = 32; off > 0; off >>= 1)
        v += __shfl_down(v, off, 64);
    if (lt == 0) red[w] = v;
    __syncthreads();
    if (t == 0) {
        float s = 0.f;
#pragma unroll
        for (int ww = 0; ww < NW; ++ww) s += red[ww];
        ws[RS_OFF + bid] = s;
    }
}

// 128 blocks (one per batch): fold the 2 row-half col partials, sum cols,
// add the batch's 2 row sums -> one float per batch. Deterministic.
__global__ __launch_bounds__(256) void colfold(float* __restrict__ ws)
{
    const int b = blockIdx.x;
    const int t = threadIdx.x;
    const float4* p0 = (const float4*)(ws + COL_OFF + (size_t)(2 * b)     * 1024) + t;
    const float4* p1 = (const float4*)(ws + COL_OFF + (size_t)(2 * b + 1) * 1024) + t;
    const float4 a = *p0;
    const float4 c = *p1;
    float v = fminf(a.x, c.x) + fminf(a.y, c.y) + fminf(a.z, c.z) + fminf(a.w, c.w);
    for (int off = 32; off > 0; off >>= 1)
        v += __shfl_down(v, off, 64);
    __shared__ float red[4];
    if ((t & 63) == 0) red[t >> 6] = v;
    __syncthreads();
    if (t == 0) {
        float s = red[0] + red[1] + red[2] + red[3];
        s += ws[RS_OFF + 2 * b] + ws[RS_OFF + 2 * b + 1];
        ws[WS2_OFF + b] = s;
    }
}

// 1 block, 128 threads: sum 128 batch totals + KLD over 4096 latents.
__global__ __launch_bounds__(128) void final_k(
    const float* __restrict__ ws,
    const float* __restrict__ mu,
    const float* __restrict__ logvar,
    float* __restrict__ out)
{
    const int t = threadIdx.x;
    float v = ws[WS2_OFF + t] * CHAMF_SCALE;

    const float4* mp = (const float4*)mu + 8 * t;     // 32 latents per thread
    const float4* lp = (const float4*)logvar + 8 * t;
    float kv = 0.f;
#pragma unroll
    for (int i = 0; i < 8; ++i) {
        const float4 mm = mp[i];
        const float4 lv = lp[i];
        kv += (1.f + lv.x - mm.x * mm.x - expf(lv.x));
        kv += (1.f + lv.y - mm.y * mm.y - expf(lv.y));
        kv += (1.f + lv.z - mm.z * mm.z - expf(lv.z));
        kv += (1.f + lv.w - mm.w * mm.w - expf(lv.w));
    }
    v += kv * KLD_SCALE;

    for (int off = 32; off > 0; off >>= 1)
        v += __shfl_down(v, off, 64);
    __shared__ float red[2];
    if ((t & 63) == 0) red[t >> 6] = v;
    __syncthreads();
    if (t == 0) out[0] = red[0] + red[1];
}

extern "C" void kernel_launch(void* const* d_in, const int* in_sizes, int n_in,
                              void* d_out, int out_size, void* d_ws, size_t ws_size,
                              hipStream_t stream) {
    const float* recon_x = (const float*)d_in[0];
    const float* x       = (const float*)d_in[1];
    const float* mu      = (const float*)d_in[2];
    const float* logvar  = (const float*)d_in[3];
    float* out = (float*)d_out;
    float* ws  = (float*)d_ws;            // uses ~1.05 MB

    chamfer_shared<<<2 * NBATCH, BT, 0, stream>>>(recon_x, x, ws);
    colfold<<<NBATCH, 256, 0, stream>>>(ws);
    final_k<<<1, 128, 0, stream>>>(ws, mu, logvar, out);
}

// Round 3
// 77.796 us; speedup vs baseline: 1.1337x; 1.0120x over previous
//
#include <hip/hip_runtime.h>

#define NUM_PTS 1024
#define NBATCH 128
#define BT 1024                       // 16 waves per block
#define NW 16
#define QW 64                         // q columns per wave (16*64 = all 1024 in-block)
#define R 8                           // rows per lane (64*8 = 512 rows/block)
#define NSTEP 64
#define RING_PAD 132                  // 128 entries + 4 pad (prefetch overrun safe)
#define CHAMF_SCALE (1.0f / 1024.0f)
#define KLD_SCALE   (-0.5f * 0.1f / 32.0f)

// ws layout (floats): [256 blocks][1024] col partials | [256] row sums | [128] batch totals
#define COL_OFF 0
#define RS_OFF  (256 * 1024)
#define WS2_OFF (RS_OFF + 256)

// R19 budget model (fits R0/R1/R2 to <0.5us): 41 fill + ~25 harness resets/gaps
// + chamfer + ~1.8 small kernels. Chamfer is ~10.5 vs 8.5us VALU-ideal; the gap
// is DS latency at 2 waves/SIMD. This round: 16-wave blocks -> 4 waves/SIMD,
// single ring/wave -> 1 ds_read + 1 bpermute per step (was 2+2), ring reused
// as row-combine LDS. Same 5.0 VALU/eval rotation scheme (verified R2).
__global__ __launch_bounds__(BT, 4) void chamfer_shared(
    const float* __restrict__ recon_x,
    const float* __restrict__ x,
    float* __restrict__ ws)
{
    const int bid = blockIdx.x;          // b*2 + rh
    const int b   = bid >> 1;
    const int rh  = bid & 1;
    const int w   = threadIdx.x >> 6;
    const int lt  = threadIdx.x & 63;
    const int t   = threadIdx.x;

    __shared__ float4 ring[NW][RING_PAD];   // 33 KB; reused as row-combine after loop
    __shared__ float  red[NW];

    // --- stage this wave's 64 q columns (recon pts), duplicated for wrap-free ring
    {
        const float* qsrc = recon_x + (size_t)b * NUM_PTS * 3 + (size_t)(w * QW + lt) * 3;
        const float qx = qsrc[0], qy = qsrc[1], qz = qsrc[2];
        const float4 q4 = make_float4(qx, qy, qz,
                                      fmaf(qx, qx, fmaf(qy, qy, qz * qz)));
        ring[w][lt]      = q4;
        ring[w][lt + 64] = q4;
    }

    // --- own 8 contiguous rows (x pts): 6 coalesced float4 loads, keep -2*coord
    const float* rp = x + (size_t)b * NUM_PTS * 3 + (size_t)rh * 512 * 3;
    float vx[R], vy[R], vz[R], r2[R], m[R];
    {
        float buf[24];
        const float4* __restrict__ s4 = (const float4*)(rp + 24 * lt);
        float4* bp = (float4*)buf;
#pragma unroll
        for (int i = 0; i < 6; ++i) bp[i] = s4[i];
#pragma unroll
        for (int k = 0; k < R; ++k) {
            vx[k] = -2.0f * buf[3 * k + 0];
            vy[k] = -2.0f * buf[3 * k + 1];
            vz[k] = -2.0f * buf[3 * k + 2];
            r2[k] = 0.25f * fmaf(vx[k], vx[k], fmaf(vy[k], vy[k], vz[k] * vz[k]));
            m[k]  = 1e30f;
        }
    }

    // --- 64 rotation steps, processed in pairs. Wave-private ring: no barrier.
    //     Step s: lane l evals q-col (l+s)&63 of this wave's window; col acc ca
    //     rotates one lane per step (after 64 rotations lane l holds col l).
    const float4* __restrict__ ringw = &ring[w][lt];
    float ca = 1e30f;
    const int rotaddr = ((lt + 1) & 63) << 2;    // new[l] = old[(l+1)&63]
    float4 qA = ringw[0];
    float4 qB = ringw[1];

#pragma unroll 4
    for (int s = 0; s < NSTEP; s += 2) {
        const float4 qC = ringw[s + 2];          // prefetch (pad makes s=62 safe)
        const float4 qD = ringw[s + 3];
        float da[R], db[R];
#pragma unroll
        for (int r = 0; r < R; ++r)
            da[r] = fmaf(vx[r], qA.x, fmaf(vy[r], qA.y, fmaf(vz[r], qA.z, r2[r] + qA.w)));
        {   // col tree step s (4x v_min3)
            const float t0 = fminf(fminf(da[0], da[1]), da[2]);
            const float t1 = fminf(fminf(da[3], da[4]), da[5]);
            const float t2 = fminf(fminf(da[6], da[7]), ca);
            ca = fminf(fminf(t0, t1), t2);
        }
        ca = __int_as_float(__builtin_amdgcn_ds_bpermute(rotaddr, __float_as_int(ca)));
#pragma unroll
        for (int r = 0; r < R; ++r)
            db[r] = fmaf(vx[r], qB.x, fmaf(vy[r], qB.y, fmaf(vz[r], qB.z, r2[r] + qB.w)));
#pragma unroll
        for (int r = 0; r < R; ++r)
            m[r] = fminf(fminf(m[r], da[r]), db[r]);       // v_min3_f32, 0.5/eval
        {   // col tree step s+1
            const float u0 = fminf(fminf(db[0], db[1]), db[2]);
            const float u1 = fminf(fminf(db[3], db[4]), db[5]);
            const float u2 = fminf(fminf(db[6], db[7]), ca);
            ca = fminf(fminf(u0, u1), u2);
        }
        ca = __int_as_float(__builtin_amdgcn_ds_bpermute(rotaddr, __float_as_int(ca)));
        qA = qC;
        qB = qD;
    }

    // --- col partials: lane l holds its own col (w*64 + l)
    ws[COL_OFF + (size_t)bid * 1024 + w * QW + lt] = ca;

    // --- row-min fold: reuse this wave's (dead, wave-private) ring slice as combine
    {
        float* mrow = (float*)&ring[w][0];       // 512 floats needed of 528 available
#pragma unroll
        for (int k = 0; k < R; ++k)
            mrow[R * lt + k] = m[k];
    }
    __syncthreads();

    float v = 0.0f;
    if (t < 512) {                               // waves 0..7, fully active
        const float* cb = (const float*)&ring[0][0];
        v = cb[t];
#pragma unroll
        for (int ww = 1; ww < NW; ++ww)
            v = fminf(v, cb[ww * (RING_PAD * 4) + t]);
        for (int off = 32; off > 0; off >>= 1)
            v += __shfl_down(v, off, 64);
        if (lt == 0) red[w] = v;
    }
    __syncthreads();
    if (t == 0) {
        float s = 0.f;
#pragma unroll
        for (int ww = 0; ww < 8; ++ww) s += red[ww];
        ws[RS_OFF + bid] = s;
    }
}

// 128 blocks (one per batch): fold the 2 row-half col partials, sum cols,
// add the batch's 2 row sums -> one float per batch. Deterministic.
__global__ __launch_bounds__(256) void colfold(float* __restrict__ ws)
{
    const int b = blockIdx.x;
    const int t = threadIdx.x;
    const float4* p0 = (const float4*)(ws + COL_OFF + (size_t)(2 * b)     * 1024) + t;
    const float4* p1 = (const float4*)(ws + COL_OFF + (size_t)(2 * b + 1) * 1024) + t;
    const float4 a = *p0;
    const float4 c = *p1;
    float v = fminf(a.x, c.x) + fminf(a.y, c.y) + fminf(a.z, c.z) + fminf(a.w, c.w);
    for (int off = 32; off > 0; off >>= 1)
        v += __shfl_down(v, off, 64);
    __shared__ float red[4];
    if ((t & 63) == 0) red[t >> 6] = v;
    __syncthreads();
    if (t == 0) {
        float s = red[0] + red[1] + red[2] + red[3];
        s += ws[RS_OFF + 2 * b] + ws[RS_OFF + 2 * b + 1];
        ws[WS2_OFF + b] = s;
    }
}

// 1 block, 128 threads: sum 128 batch totals + KLD over 4096 latents.
__global__ __launch_bounds__(128) void final_k(
    const float* __restrict__ ws,
    const float* __restrict__ mu,
    const float* __restrict__ logvar,
    float* __restrict__ out)
{
    const int t = threadIdx.x;
    float v = ws[WS2_OFF + t] * CHAMF_SCALE;

    const float4* mp = (const float4*)mu + 8 * t;     // 32 latents per thread
    const float4* lp = (const float4*)logvar + 8 * t;
    float kv = 0.f;
#pragma unroll
    for (int i = 0; i < 8; ++i) {
        const float4 mm = mp[i];
        const float4 lv = lp[i];
        kv += (1.f + lv.x - mm.x * mm.x - expf(lv.x));
        kv += (1.f + lv.y - mm.y * mm.y - expf(lv.y));
        kv += (1.f + lv.z - mm.z * mm.z - expf(lv.z));
        kv += (1.f + lv.w - mm.w * mm.w - expf(lv.w));
    }
    v += kv * KLD_SCALE;

    for (int off = 32; off > 0; off >>= 1)
        v += __shfl_down(v, off, 64);
    __shared__ float red[2];
    if ((t & 63) == 0) red[t >> 6] = v;
    __syncthreads();
    if (t == 0) out[0] = red[0] + red[1];
}

extern "C" void kernel_launch(void* const* d_in, const int* in_sizes, int n_in,
                              void* d_out, int out_size, void* d_ws, size_t ws_size,
                              hipStream_t stream) {
    const float* recon_x = (const float*)d_in[0];
    const float* x       = (const float*)d_in[1];
    const float* mu      = (const float*)d_in[2];
    const float* logvar  = (const float*)d_in[3];
    float* out = (float*)d_out;
    float* ws  = (float*)d_ws;            // uses ~1.05 MB

    chamfer_shared<<<2 * NBATCH, BT, 0, stream>>>(recon_x, x, ws);
    colfold<<<NBATCH, 256, 0, stream>>>(ws);
    final_k<<<1, 128, 0, stream>>>(ws, mu, logvar, out);
}